// Round 9
// baseline (3332.639 us; speedup 1.0000x reference)
//
#include <hip/hip_runtime.h>
#include <math.h>
#include <stdint.h>

#define BB 32
#define TT 2048
#define FF 128
#define HH 512
#define FCC 128
#define QW 8
#define NTH 640   // 10 waves: 0-7 compute+add, 8 reader, 9 scorer (q==0) / barrier-idle

#define SCALE_F     4194304.0f             // 2^22 fixed-point scale (i32-decodable)
#define INV_SCALE_F (1.0f/4194304.0f)
#define CNT_ONE     (1ull<<48)             // arrival counter increment
#define BIAS_TOTAL  (1ll<<46)              // keeps low field positive: no carry into bit 48
#define BIAS_SHARE  (1ll<<43)              // BIAS_TOTAL / 8 (one share per WG, first use of each parity)
// 2^46 and 2^43 are both ≡ 0 mod 2^32, and |A·2^22| < 2^31, so the reader
// decodes the signed sum as (int32)(low 32 bits) — no 64-bit ops needed.

#define WS_U64 (2*BB*HH + BB*16*8 + BB)    // gh + gsd + gx handshake

typedef float f32x2 __attribute__((ext_vector_type(2)));

__global__ void ws_zero(uint64_t* g) {     // counters/tags must start at 0 (0xAA poison aliases)
    size_t i = (size_t)blockIdx.x * blockDim.x + threadIdx.x;
    if (i < WS_U64) g[i] = 0ull;
}

__device__ __forceinline__ void wait_lgkm0() {
    asm volatile("s_waitcnt lgkmcnt(0)" ::: "memory");
}

// raw WG barrier: NO implicit vmcnt drain (fire-and-forget adds stay in
// flight). Compile-level memory fences on both sides so LDS ops can't be
// scheduled across it.
__device__ __forceinline__ void wg_barrier() {
    asm volatile("" ::: "memory");
    __builtin_amdgcn_s_barrier();
    asm volatile("" ::: "memory");
}

__device__ __forceinline__ float fast_tanh(float z) {
    float ax = fabsf(z);
    float e  = __expf(-2.0f * ax);
    float r  = (1.0f - e) / (1.0f + e);
    return copysignf(r, z);
}

// packed f32 FMA: d.lo += a.lo*b.lo, d.hi += a.hi*b.hi  (full-rate on CDNA4)
__device__ __forceinline__ void pk_fma(f32x2& d, f32x2 a, f32x2 b) {
    asm("v_pk_fma_f32 %0, %1, %2, %0" : "+v"(d) : "v"(a), "v"(b));
}
__device__ __forceinline__ f32x2 lo2(float4 v) { f32x2 r; r.x = v.x; r.y = v.y; return r; }
__device__ __forceinline__ f32x2 hi2(float4 v) { f32x2 r; r.x = v.z; r.y = v.w; return r; }

__device__ __forceinline__ uint64_t gld_agent(const uint64_t* p) {
    return __hip_atomic_load(p, __ATOMIC_RELAXED, __HIP_MEMORY_SCOPE_AGENT);
}

// IC-gather RNN. grid=256 (1 WG/CU). XCD-local mapping: b=blk&31, q=blk>>5
// puts all 8 WGs of batch b at blk ≡ b (mod 8) -> same XCD under round-robin
// dispatch. Startup handshake VERIFIES this (correctness never assumes it):
// wave8 reads HW_REG_XCC_ID, adds 1<<(8*xcc) into gx[b], waits byte-sum==8;
// lok iff all 8 arrivals in its OWN byte. If lok: accumulator protocol runs
// with WORKGROUP-scope atomics at the shared XCD L2 (RT ~200cy vs LLC
// ~600cy). Fallback: agent scope (R3-verified).
// Per step i (h_i in LDS, guaranteed by the PER-STEP RAW BARRIER):
//   waves 0-7 (row r=w*64+lane): packed-FMA A = W_hh[r][own 64 cols]·h_i +
//     W_ih[r][own 16 cols]·x_i (x-part precomputed LAST iter; 4 independent
//     FMA chains, dep depth 8), i32 fixed-point delta vs same-parity 2 steps
//     ago, ONE fire-and-forget atomic_add((1<<48)|delta) to
//     slot[(i+1)&1][b][r]; then next x-part; barrier.
//   wave 8 (prio 1): 2-DEEP uniform-exit RMW(+0) poll, SEEDED by a cross-
//     step L2-local prefetch RMW (issued after last detect; flight hidden
//     under tanh+barrier+MAC). Sampling interval ~RT/2. Plain C + __all
//     exits (R1/R2 lesson: no asm register games); exact == check safe:
//     single consumer per group + barrier causality -> no overshoot before
//     detect (adds for next use are gated on this wave's own barrier).
//     RMW(+0) value-neutral. R4's poison avoided: depth 2 (not 4),
//     XCD-L2 (not LLC), RMW (no L1 staleness). Decode (int32)low32, +bias,
//     tanh, write LDS h[(i+1)&1], lgkmcnt(0), barrier.
//   wave 7 extra: publishes chunk-dot of h_i (tagged u64, agent scope) into
//     16-deep ring (in the reader-poll shadow: post-add, pre-barrier).
//   wave 9 q==0: NON-BLOCKING pipelined ring consume — checks LAST iter's
//     loads, consumes ≤1 step/iter, reissues, barriers; blocking drain
//     post-loop.  wave 9 q!=0: barrier-idles len times.
// Barrier-WAR safety: reader writes parity P at iter i; computes read P at
// iter i+1 (post-barrier-i); reader rewrites P at iter i+2, after barrier
// i+1, which requires computes' reads retired (data-dep before their add).
// Every wave executes exactly len barriers + initial __syncthreads.
// Parity-slot reuse safe (read->barrier->compute->add causality). Carry-safe
// packing: low field = 2^46 + S*2^22, |S|<2^9.
__global__ __launch_bounds__(NTH, 1)
void rnn_seq(const float* __restrict__ x, const int* __restrict__ lengths,
             const float* __restrict__ W_ih, const float* __restrict__ W_hh,
             const float* __restrict__ b_ih, const float* __restrict__ b_hh,
             const float* __restrict__ W1, const float* __restrict__ b1,
             const float* __restrict__ W2, const float* __restrict__ b2,
             float* __restrict__ out, uint64_t* __restrict__ ws)
{
    const int blk  = blockIdx.x;
    const int b    = blk & 31;      // batch: all 8 WGs of b share blk%8 -> same XCD
    const int q    = blk >> 5;      // col-chunk owned by this WG
    const int tid  = threadIdx.x;
    const int w    = tid >> 6;
    const int lane = tid & 63;
    const int len  = lengths[b];

    uint64_t* gh  = ws;                         // [2][BB][HH] row accumulators
    uint64_t* gsd = ws + 2 * BB * HH;           // [BB][16][8] scorer ring
    uint64_t* gx  = gsd + BB * 16 * 8;          // [BB] xcd handshake

    __shared__ float hsh[2][64];                // h chunk, 2-parity
    __shared__ float biass[64];
    __shared__ int   lok_s;                     // 1 = all 8 WGs on this XCD

    if (w == 8) {
        biass[lane] = b_ih[q * 64 + lane] + b_hh[q * 64 + lane];
        hsh[0][lane] = 0.0f;                    // h_0 = 0
        uint32_t xcc_raw;
        asm volatile("s_getreg_b32 %0, hwreg(HW_REG_XCC_ID)" : "=s"(xcc_raw));
        const uint32_t xcc = xcc_raw & 7;
        if (lane == 0) {
            uint64_t* gxp = gx + b;
            __hip_atomic_fetch_add(gxp, 1ull << (8 * xcc),
                                   __ATOMIC_RELAXED, __HIP_MEMORY_SCOPE_AGENT);
            uint64_t v;
            do { v = gld_agent(gxp); }
            while ((uint8_t)((v * 0x0101010101010101ull) >> 56) != 8);
            lok_s = (v == (8ull << (8 * xcc))) ? 1 : 0;
        }
    }
    __syncthreads();
    const bool lok = (lok_s != 0);

    if (w < 8) {
        // ================= compute+add role: row r =================
        const int r = w * 64 + lane;
        float4 ww[16];
        { const float4* p = (const float4*)(W_hh + (size_t)r * HH + q * 64);
          #pragma unroll
          for (int k = 0; k < 16; ++k) ww[k] = p[k]; }
        float4 wi[4];
        { const float4* p = (const float4*)(W_ih + r * FF + q * 16);
          #pragma unroll
          for (int k = 0; k < 4; ++k) wi[k] = p[k]; }
        float wvreg = 0.0f;
        if (w == 7) {                           // scorer weight for col q*64+lane
            const int col = q * 64 + lane;
            #pragma unroll 8
            for (int f = 0; f < FCC; ++f) wvreg += W2[f] * W1[f * HH + col];
        }
        int prevI[2] = {0, 0};
        const float* xb = x + (size_t)b * TT * FF + q * 16;
        float4 xc[4], xn[4];
        { const float4* p = (const float4*)xb;
          #pragma unroll
          for (int k = 0; k < 4; ++k) xc[k] = p[k]; }
        { const float4* p = (const float4*)(xb + FF);
          #pragma unroll
          for (int k = 0; k < 4; ++k) xn[k] = p[k]; }

        uint64_t* ghb = gh + (size_t)b * HH + r;

        // x-part for i=0 (pre-loop; thereafter computed at end of prev iter)
        // 4 independent accumulator chains (a0..a3); x-part feeds a0/a1.
        f32x2 a0 = {0.0f, 0.0f}, a1 = {0.0f, 0.0f};
        f32x2 a2 = {0.0f, 0.0f}, a3 = {0.0f, 0.0f};
        #pragma unroll
        for (int k = 0; k < 4; ++k) {
            pk_fma(a0, lo2(wi[k]), lo2(xc[k]));
            pk_fma(a1, hi2(wi[k]), hi2(xc[k]));
        }

        for (int i = 0; i < len; ++i) {
            // h_i ready in hsh[i&1] (initial sync / previous barrier)
            const float* hc = hsh[i & 1];
            const float4* hq = (const float4*)hc;
            #pragma unroll
            for (int k = 0; k < 16; k += 2) {
                float4 hk0 = hq[k];
                float4 hk1 = hq[k + 1];
                pk_fma(a0, lo2(ww[k]),     lo2(hk0));
                pk_fma(a1, hi2(ww[k]),     hi2(hk0));
                pk_fma(a2, lo2(ww[k + 1]), lo2(hk1));
                pk_fma(a3, hi2(ww[k + 1]), hi2(hk1));
            }
            float A = ((a0.x + a0.y) + (a1.x + a1.y))
                    + ((a2.x + a2.y) + (a3.x + a3.y));

            float hown = 0.0f;
            if (w == 7) hown = hc[lane];        // capture h_i for scorer dot

            int fi = __float2int_rn(A * SCALE_F);
            const int pn = (i + 1) & 1;
            long long con = (long long)CNT_ONE + (long long)(fi - prevI[pn])
                          + ((i < 2) ? BIAS_SHARE : 0);
            prevI[pn] = fi;
            uint64_t* slot = ghb + (size_t)pn * BB * HH;
            if (lok)                             // L2-local RMW (same-XCD verified)
                __hip_atomic_fetch_add(slot, (uint64_t)con,
                                       __ATOMIC_RELAXED, __HIP_MEMORY_SCOPE_WORKGROUP);
            else
                atomicAdd((unsigned long long*)slot, (unsigned long long)con);

            if (w == 7 && i > 0) {              // scorer chunk-dot of h_i
                float d = hown * wvreg;
                d += __shfl_xor(d, 1);  d += __shfl_xor(d, 2);
                d += __shfl_xor(d, 4);  d += __shfl_xor(d, 8);
                d += __shfl_xor(d, 16); d += __shfl_xor(d, 32);
                if (lane == 0) {
                    uint64_t pk = ((uint64_t)(uint32_t)i << 32) |
                                  (uint64_t)__float_as_uint(d);
                    __hip_atomic_store(&gsd[((size_t)b * 16 + (i & 15)) * 8 + q],
                                       pk, __ATOMIC_RELAXED, __HIP_MEMORY_SCOPE_AGENT);
                }
            }
            // ---- next-iter x prep + x-part: overlaps the reader's poll
            #pragma unroll
            for (int k = 0; k < 4; ++k) xc[k] = xn[k];
            if (i + 2 < len) {
                const float4* p = (const float4*)(xb + (size_t)(i + 2) * FF);
                #pragma unroll
                for (int k = 0; k < 4; ++k) xn[k] = p[k];
            }
            a0.x = 0.0f; a0.y = 0.0f; a1.x = 0.0f; a1.y = 0.0f;
            a2.x = 0.0f; a2.y = 0.0f; a3.x = 0.0f; a3.y = 0.0f;
            #pragma unroll
            for (int k = 0; k < 4; ++k) {
                pk_fma(a0, lo2(wi[k]), lo2(xc[k]));
                pk_fma(a1, hi2(wi[k]), hi2(xc[k]));
            }
            wg_barrier();
        }
        if (w == 7) {                            // final scorer dot: h_len
            // h_len visible: last barrier released after reader wrote it
            float d = hsh[len & 1][lane] * wvreg;
            d += __shfl_xor(d, 1);  d += __shfl_xor(d, 2);
            d += __shfl_xor(d, 4);  d += __shfl_xor(d, 8);
            d += __shfl_xor(d, 16); d += __shfl_xor(d, 32);
            if (lane == 0) {
                uint64_t pk = ((uint64_t)(uint32_t)len << 32) |
                              (uint64_t)__float_as_uint(d);
                __hip_atomic_store(&gsd[((size_t)b * 16 + (len & 15)) * 8 + q],
                                   pk, __ATOMIC_RELAXED, __HIP_MEMORY_SCOPE_AGENT);
            }
        }
    } else if (w == 8) {
        // ================= reader role: own 64 slots =================
        __builtin_amdgcn_s_setprio(1);          // win SIMD arbitration
        uint64_t z = 0;
        asm("" : "+v"(z));                      // opaque zero: keeps fetch_add a real RMW
        float hval = 0.0f;
        uint64_t upre = 0;                      // cross-step prefetch (tag 0 < any target)
        for (int i = 0; i < len; ++i) {
            const int j  = i + 1;
            const int pn = j & 1;
            const uint64_t target = 8ull * (uint64_t)((j + 1) >> 1); // 8*uses of this parity
            uint64_t* pr = gh + (size_t)pn * BB * HH + (size_t)b * HH + q * 64 + lane;
            uint64_t u;
            if (lok) {
                // 2-deep uniform poll: seed (L2-fresh prefetch) + one new
                // in-flight RMW; reissue alternately -> sample every ~RT/2.
                uint64_t u0 = upre;
                uint64_t u1 = __hip_atomic_fetch_add(pr, z, __ATOMIC_RELAXED,
                                                     __HIP_MEMORY_SCOPE_WORKGROUP);
                for (;;) {
                    if (__all((u0 >> 48) == target)) { u = u0; break; }
                    u0 = __hip_atomic_fetch_add(pr, z, __ATOMIC_RELAXED,
                                                __HIP_MEMORY_SCOPE_WORKGROUP);
                    if (__all((u1 >> 48) == target)) { u = u1; break; }
                    u1 = __hip_atomic_fetch_add(pr, z, __ATOMIC_RELAXED,
                                                __HIP_MEMORY_SCOPE_WORKGROUP);
                }
            } else {
                u = upre;
                while ((u >> 48) != target) u = gld_agent(pr);
            }
            // issue ONE L2-local prefetch RMW for step j+1 (other parity);
            // flight hides under tanh+barrier+MAC. Value-neutral (+0); stale
            // or incomplete tag -> next iter's poll takes over.
            if (i + 1 < len) {
                uint64_t* prn = gh + (size_t)((j + 1) & 1) * BB * HH
                              + (size_t)b * HH + q * 64 + lane;
                upre = lok ? __hip_atomic_fetch_add(prn, z, __ATOMIC_RELAXED,
                                                    __HIP_MEMORY_SCOPE_WORKGROUP)
                           : gld_agent(prn);
            }
            // i32 decode: 2^46/2^43 bias ≡ 0 mod 2^32, |S·2^22| < 2^31
            float pre = (float)(int)(uint32_t)u * INV_SCALE_F + biass[lane];
            hval = fast_tanh(pre);
            hsh[pn][lane] = hval;
            wait_lgkm0();                       // h write visible before release
            wg_barrier();
        }
        out[BB + b * HH + q * 64 + lane] = hval;   // h_final chunk
    } else if (q == 0) {
        // ========== scorer (q==0): non-blocking pipelined consume ==========
        float cconst = b2[0];
        for (int f = 0; f < FCC; ++f) cconst += W2[f] * b1[f];
        int count = 0;
        int jn = 1;
        uint64_t upend = 0;                     // tag 0 never matches jn>=1
        for (int i = 0; i < len; ++i) {
            // check LAST iter's loads (full iter of flight ≫ LLC RT)
            bool ok = (lane < 8) ? ((int)(upend >> 32) == jn) : true;
            if (__all(ok)) {
                float d = (lane < 8) ? __uint_as_float((uint32_t)upend) : 0.0f;
                d += __shfl_xor(d, 1); d += __shfl_xor(d, 2); d += __shfl_xor(d, 4);
                if (lane == 0 && d + cconst > 0.0f) ++count;
                ++jn;
            }
            // reissue for (possibly advanced) jn — checked next iter
            upend = (lane < 8)
                  ? gld_agent(gsd + ((size_t)b * 16 + (jn & 15)) * 8 + lane)
                  : 0ull;
            wg_barrier();
        }
        // drain the tail (blocking; producers' final publishes in flight)
        while (jn <= len) {
            float d = 0.0f;
            if (lane < 8) {
                uint64_t* pr = gsd + ((size_t)b * 16 + (jn & 15)) * 8 + lane;
                uint64_t u;
                do { u = gld_agent(pr); } while ((int)(u >> 32) != jn);
                d = __uint_as_float((uint32_t)u);
            }
            d += __shfl_xor(d, 1); d += __shfl_xor(d, 2); d += __shfl_xor(d, 4);
            if (lane == 0 && d + cconst > 0.0f) ++count;
            ++jn;
        }
        if (lane == 0) out[b] = (float)count;
    } else {
        // ====== wave 9, q!=0: barrier-idle (early return would hang) ======
        for (int i = 0; i < len; ++i) wg_barrier();
    }
}

extern "C" void kernel_launch(void* const* d_in, const int* in_sizes, int n_in,
                              void* d_out, int out_size, void* d_ws, size_t ws_size,
                              hipStream_t stream) {
    const float* x    = (const float*)d_in[0];
    const int*   lens = (const int*)d_in[1];
    const float* W_ih = (const float*)d_in[2];
    const float* W_hh = (const float*)d_in[3];
    const float* b_ih = (const float*)d_in[4];
    const float* b_hh = (const float*)d_in[5];
    const float* W1   = (const float*)d_in[6];
    const float* b1   = (const float*)d_in[7];
    const float* W2   = (const float*)d_in[8];
    const float* b2   = (const float*)d_in[9];
    float* out = (float*)d_out;
    uint64_t* ws = (uint64_t*)d_ws;   // WS_U64 u64 = 295168 B

    ws_zero<<<dim3(145), dim3(256), 0, stream>>>(ws);
    rnn_seq<<<dim3(BB * QW), dim3(NTH), 0, stream>>>(
        x, lens, W_ih, W_hh, b_ih, b_hh, W1, b1, W2, b2, out, ws);
}

// Round 10
// 2709.722 us; speedup vs baseline: 1.2299x; 1.2299x over previous
//
#include <hip/hip_runtime.h>
#include <math.h>
#include <stdint.h>

#define BB 32
#define TT 2048
#define FF 128
#define HH 512
#define FCC 128
#define QW 8
#define NTH 640   // 10 waves: 0-7 compute+add, 8 reader, 9 scorer (q==0) / barrier-idle

#define SCALE_F     4194304.0f             // 2^22 fixed-point scale (i32-decodable)
#define INV_SCALE_F (1.0f/4194304.0f)
#define CNT_ONE     (1ull<<48)             // arrival counter increment
#define BIAS_TOTAL  (1ll<<46)              // keeps low field positive: no carry into bit 48
#define BIAS_SHARE  (1ll<<43)              // BIAS_TOTAL / 8 (one share per WG, first use of each parity)
// 2^46 and 2^43 are both ≡ 0 mod 2^32, and |A·2^22| < 2^31, so the reader
// decodes the signed sum as (int32)(low 32 bits) — no 64-bit ops needed.

#define WS_U64 (2*BB*HH + BB*16*8 + BB)    // gh + gsd + gx handshake

typedef float f32x2 __attribute__((ext_vector_type(2)));

__global__ void ws_zero(uint64_t* g) {     // counters/tags must start at 0 (0xAA poison aliases)
    size_t i = (size_t)blockIdx.x * blockDim.x + threadIdx.x;
    if (i < WS_U64) g[i] = 0ull;
}

__device__ __forceinline__ void wait_lgkm0() {
    asm volatile("s_waitcnt lgkmcnt(0)" ::: "memory");
}

// raw WG barrier: NO implicit vmcnt drain (fire-and-forget adds stay in
// flight). Compile-level memory fences on both sides so LDS ops can't be
// scheduled across it.
__device__ __forceinline__ void wg_barrier() {
    asm volatile("" ::: "memory");
    __builtin_amdgcn_s_barrier();
    asm volatile("" ::: "memory");
}

__device__ __forceinline__ float fast_tanh(float z) {
    float ax = fabsf(z);
    float e  = __expf(-2.0f * ax);
    float r  = (1.0f - e) / (1.0f + e);
    return copysignf(r, z);
}

// packed f32 FMA: d.lo += a.lo*b.lo, d.hi += a.hi*b.hi  (full-rate on CDNA4)
__device__ __forceinline__ void pk_fma(f32x2& d, f32x2 a, f32x2 b) {
    asm("v_pk_fma_f32 %0, %1, %2, %0" : "+v"(d) : "v"(a), "v"(b));
}
__device__ __forceinline__ f32x2 lo2(float4 v) { f32x2 r; r.x = v.x; r.y = v.y; return r; }
__device__ __forceinline__ f32x2 hi2(float4 v) { f32x2 r; r.x = v.z; r.y = v.w; return r; }

__device__ __forceinline__ uint64_t gld_agent(const uint64_t* p) {
    return __hip_atomic_load(p, __ATOMIC_RELAXED, __HIP_MEMORY_SCOPE_AGENT);
}

// IC-gather RNN. grid=256 (1 WG/CU). XCD-local mapping: b=blk&31, q=blk>>5
// puts all 8 WGs of batch b at blk ≡ b (mod 8) -> same XCD under round-robin
// dispatch. Startup handshake VERIFIES this (correctness never assumes it):
// wave8 reads HW_REG_XCC_ID, adds 1<<(8*xcc) into gx[b], waits byte-sum==8;
// lok iff all 8 arrivals in its OWN byte. If lok: accumulator protocol runs
// with WORKGROUP-scope atomics at the shared XCD L2 (RT ~200cy vs LLC
// ~600cy). Fallback: agent scope (R3-verified).
//
// POLL INVARIANT (R4 @LLC, R9 @L2, both ~+10-35% regressions): the
// accumulator lines tolerate exactly ONE outstanding reader RMW. Deeper /
// prefetch RMW polling serializes with the 8 producer adds at the L2 atomic
// unit and delays the very completion being polled (R9: WRITE_SIZE
// 1.44->2.04 GB, +36% time).
//
// Per step i (h_i in LDS, guaranteed by the PER-STEP RAW BARRIER):
//   waves 0-7 (row r=w*64+lane): packed-FMA A = W_hh[r][own 64 cols]·h_i +
//     W_ih[r][own 16 cols]·x_i (x-part precomputed LAST iter; 4 independent
//     FMA chains, dep depth 8), i32 fixed-point delta vs same-parity 2 steps
//     ago, ONE fire-and-forget atomic_add((1<<48)|delta) to
//     slot[(i+1)&1][b][r]; then next x-part; barrier. (Post-add work hides
//     under the reader's detect — reader is always last to the barrier.)
//   wave 8 (prio 1): s_sleep(2) (~128cy, skips the dead window where adds
//     cannot yet have landed -> first probe departs ~aligned with
//     completion instead of wasting a full RT in-flight), then verified
//     single-outstanding RMW(+0) do-while poll until counter==8*uses.
//     Decode (int32)low32, +bias, tanh, write LDS h[(i+1)&1], lgkmcnt(0),
//     barrier.
//   wave 7 extra: publishes chunk-dot of h_i (tagged u64, agent scope) into
//     16-deep ring (post-add, pre-barrier: in the reader-detect shadow).
//   wave 9 q==0: NON-BLOCKING pipelined ring consume — checks LAST iter's
//     loads, consumes ≤1 step/iter, reissues, barriers; blocking drain
//     post-loop.  wave 9 q!=0: barrier-idles len times.
// Barrier-WAR safety: reader writes parity P at iter i; computes read P at
// iter i+1 (post-barrier-i); reader rewrites P at iter i+2, after barrier
// i+1, which requires computes' reads retired (data-dep before their add).
// Every wave executes exactly len barriers + initial __syncthreads.
// Parity-slot reuse safe (read->barrier->compute->add causality). Carry-safe
// packing: low field = 2^46 + S*2^22, |S|<2^9.
__global__ __launch_bounds__(NTH, 1)
void rnn_seq(const float* __restrict__ x, const int* __restrict__ lengths,
             const float* __restrict__ W_ih, const float* __restrict__ W_hh,
             const float* __restrict__ b_ih, const float* __restrict__ b_hh,
             const float* __restrict__ W1, const float* __restrict__ b1,
             const float* __restrict__ W2, const float* __restrict__ b2,
             float* __restrict__ out, uint64_t* __restrict__ ws)
{
    const int blk  = blockIdx.x;
    const int b    = blk & 31;      // batch: all 8 WGs of b share blk%8 -> same XCD
    const int q    = blk >> 5;      // col-chunk owned by this WG
    const int tid  = threadIdx.x;
    const int w    = tid >> 6;
    const int lane = tid & 63;
    const int len  = lengths[b];

    uint64_t* gh  = ws;                         // [2][BB][HH] row accumulators
    uint64_t* gsd = ws + 2 * BB * HH;           // [BB][16][8] scorer ring
    uint64_t* gx  = gsd + BB * 16 * 8;          // [BB] xcd handshake

    __shared__ float hsh[2][64];                // h chunk, 2-parity
    __shared__ float biass[64];
    __shared__ int   lok_s;                     // 1 = all 8 WGs on this XCD

    if (w == 8) {
        biass[lane] = b_ih[q * 64 + lane] + b_hh[q * 64 + lane];
        hsh[0][lane] = 0.0f;                    // h_0 = 0
        uint32_t xcc_raw;
        asm volatile("s_getreg_b32 %0, hwreg(HW_REG_XCC_ID)" : "=s"(xcc_raw));
        const uint32_t xcc = xcc_raw & 7;
        if (lane == 0) {
            uint64_t* gxp = gx + b;
            __hip_atomic_fetch_add(gxp, 1ull << (8 * xcc),
                                   __ATOMIC_RELAXED, __HIP_MEMORY_SCOPE_AGENT);
            uint64_t v;
            do { v = gld_agent(gxp); }
            while ((uint8_t)((v * 0x0101010101010101ull) >> 56) != 8);
            lok_s = (v == (8ull << (8 * xcc))) ? 1 : 0;
        }
    }
    __syncthreads();
    const bool lok = (lok_s != 0);

    if (w < 8) {
        // ================= compute+add role: row r =================
        const int r = w * 64 + lane;
        float4 ww[16];
        { const float4* p = (const float4*)(W_hh + (size_t)r * HH + q * 64);
          #pragma unroll
          for (int k = 0; k < 16; ++k) ww[k] = p[k]; }
        float4 wi[4];
        { const float4* p = (const float4*)(W_ih + r * FF + q * 16);
          #pragma unroll
          for (int k = 0; k < 4; ++k) wi[k] = p[k]; }
        float wvreg = 0.0f;
        if (w == 7) {                           // scorer weight for col q*64+lane
            const int col = q * 64 + lane;
            #pragma unroll 8
            for (int f = 0; f < FCC; ++f) wvreg += W2[f] * W1[f * HH + col];
        }
        int prevI[2] = {0, 0};
        const float* xb = x + (size_t)b * TT * FF + q * 16;
        float4 xc[4], xn[4];
        { const float4* p = (const float4*)xb;
          #pragma unroll
          for (int k = 0; k < 4; ++k) xc[k] = p[k]; }
        { const float4* p = (const float4*)(xb + FF);
          #pragma unroll
          for (int k = 0; k < 4; ++k) xn[k] = p[k]; }

        uint64_t* ghb = gh + (size_t)b * HH + r;

        // x-part for i=0 (pre-loop; thereafter computed at end of prev iter)
        // 4 independent accumulator chains (a0..a3); x-part feeds a0/a1.
        f32x2 a0 = {0.0f, 0.0f}, a1 = {0.0f, 0.0f};
        f32x2 a2 = {0.0f, 0.0f}, a3 = {0.0f, 0.0f};
        #pragma unroll
        for (int k = 0; k < 4; ++k) {
            pk_fma(a0, lo2(wi[k]), lo2(xc[k]));
            pk_fma(a1, hi2(wi[k]), hi2(xc[k]));
        }

        for (int i = 0; i < len; ++i) {
            // h_i ready in hsh[i&1] (initial sync / previous barrier)
            const float* hc = hsh[i & 1];
            const float4* hq = (const float4*)hc;
            #pragma unroll
            for (int k = 0; k < 16; k += 2) {
                float4 hk0 = hq[k];
                float4 hk1 = hq[k + 1];
                pk_fma(a0, lo2(ww[k]),     lo2(hk0));
                pk_fma(a1, hi2(ww[k]),     hi2(hk0));
                pk_fma(a2, lo2(ww[k + 1]), lo2(hk1));
                pk_fma(a3, hi2(ww[k + 1]), hi2(hk1));
            }
            float A = ((a0.x + a0.y) + (a1.x + a1.y))
                    + ((a2.x + a2.y) + (a3.x + a3.y));

            float hown = 0.0f;
            if (w == 7) hown = hc[lane];        // capture h_i for scorer dot

            int fi = __float2int_rn(A * SCALE_F);
            const int pn = (i + 1) & 1;
            long long con = (long long)CNT_ONE + (long long)(fi - prevI[pn])
                          + ((i < 2) ? BIAS_SHARE : 0);
            prevI[pn] = fi;
            uint64_t* slot = ghb + (size_t)pn * BB * HH;
            if (lok)                             // L2-local RMW (same-XCD verified)
                __hip_atomic_fetch_add(slot, (uint64_t)con,
                                       __ATOMIC_RELAXED, __HIP_MEMORY_SCOPE_WORKGROUP);
            else
                atomicAdd((unsigned long long*)slot, (unsigned long long)con);

            if (w == 7 && i > 0) {              // scorer chunk-dot of h_i
                float d = hown * wvreg;
                d += __shfl_xor(d, 1);  d += __shfl_xor(d, 2);
                d += __shfl_xor(d, 4);  d += __shfl_xor(d, 8);
                d += __shfl_xor(d, 16); d += __shfl_xor(d, 32);
                if (lane == 0) {
                    uint64_t pk = ((uint64_t)(uint32_t)i << 32) |
                                  (uint64_t)__float_as_uint(d);
                    __hip_atomic_store(&gsd[((size_t)b * 16 + (i & 15)) * 8 + q],
                                       pk, __ATOMIC_RELAXED, __HIP_MEMORY_SCOPE_AGENT);
                }
            }
            // ---- next-iter x prep + x-part: overlaps the reader's poll
            #pragma unroll
            for (int k = 0; k < 4; ++k) xc[k] = xn[k];
            if (i + 2 < len) {
                const float4* p = (const float4*)(xb + (size_t)(i + 2) * FF);
                #pragma unroll
                for (int k = 0; k < 4; ++k) xn[k] = p[k];
            }
            a0.x = 0.0f; a0.y = 0.0f; a1.x = 0.0f; a1.y = 0.0f;
            a2.x = 0.0f; a2.y = 0.0f; a3.x = 0.0f; a3.y = 0.0f;
            #pragma unroll
            for (int k = 0; k < 4; ++k) {
                pk_fma(a0, lo2(wi[k]), lo2(xc[k]));
                pk_fma(a1, hi2(wi[k]), hi2(xc[k]));
            }
            wg_barrier();
        }
        if (w == 7) {                            // final scorer dot: h_len
            // h_len visible: last barrier released after reader wrote it
            float d = hsh[len & 1][lane] * wvreg;
            d += __shfl_xor(d, 1);  d += __shfl_xor(d, 2);
            d += __shfl_xor(d, 4);  d += __shfl_xor(d, 8);
            d += __shfl_xor(d, 16); d += __shfl_xor(d, 32);
            if (lane == 0) {
                uint64_t pk = ((uint64_t)(uint32_t)len << 32) |
                              (uint64_t)__float_as_uint(d);
                __hip_atomic_store(&gsd[((size_t)b * 16 + (len & 15)) * 8 + q],
                                   pk, __ATOMIC_RELAXED, __HIP_MEMORY_SCOPE_AGENT);
            }
        }
    } else if (w == 8) {
        // ================= reader role: own 64 slots =================
        __builtin_amdgcn_s_setprio(1);          // win SIMD arbitration
        uint64_t z = 0;
        asm("" : "+v"(z));                      // opaque zero: keeps fetch_add a real RMW
        float hval = 0.0f;
        for (int i = 0; i < len; ++i) {
            const int j  = i + 1;
            const int pn = j & 1;
            const uint64_t target = 8ull * (uint64_t)((j + 1) >> 1); // 8*uses of this parity
            uint64_t* pr = gh + (size_t)pn * BB * HH + (size_t)b * HH + q * 64 + lane;
            uint64_t u;
            if (lok) {
                // skip the dead window (adds can't land before ~MAC+flight):
                // first probe departs near completion instead of mid-flight.
                __builtin_amdgcn_s_sleep(2);    // ~128 cy
                // verified single-outstanding RMW(+0) poll (POLL INVARIANT).
                do { u = __hip_atomic_fetch_add(pr, z, __ATOMIC_RELAXED,
                                                __HIP_MEMORY_SCOPE_WORKGROUP); }
                while ((u >> 48) != target);
            } else {
                do { u = gld_agent(pr); } while ((u >> 48) != target);
            }
            // i32 decode: 2^46/2^43 bias ≡ 0 mod 2^32, |S·2^22| < 2^31
            float pre = (float)(int)(uint32_t)u * INV_SCALE_F + biass[lane];
            hval = fast_tanh(pre);
            hsh[pn][lane] = hval;
            wait_lgkm0();                       // h write visible before release
            wg_barrier();
        }
        out[BB + b * HH + q * 64 + lane] = hval;   // h_final chunk
    } else if (q == 0) {
        // ========== scorer (q==0): non-blocking pipelined consume ==========
        float cconst = b2[0];
        for (int f = 0; f < FCC; ++f) cconst += W2[f] * b1[f];
        int count = 0;
        int jn = 1;
        uint64_t upend = 0;                     // tag 0 never matches jn>=1
        for (int i = 0; i < len; ++i) {
            // check LAST iter's loads (full iter of flight ≫ LLC RT)
            bool ok = (lane < 8) ? ((int)(upend >> 32) == jn) : true;
            if (__all(ok)) {
                float d = (lane < 8) ? __uint_as_float((uint32_t)upend) : 0.0f;
                d += __shfl_xor(d, 1); d += __shfl_xor(d, 2); d += __shfl_xor(d, 4);
                if (lane == 0 && d + cconst > 0.0f) ++count;
                ++jn;
            }
            // reissue for (possibly advanced) jn — checked next iter
            upend = (lane < 8)
                  ? gld_agent(gsd + ((size_t)b * 16 + (jn & 15)) * 8 + lane)
                  : 0ull;
            wg_barrier();
        }
        // drain the tail (blocking; producers' final publishes in flight)
        while (jn <= len) {
            float d = 0.0f;
            if (lane < 8) {
                uint64_t* pr = gsd + ((size_t)b * 16 + (jn & 15)) * 8 + lane;
                uint64_t u;
                do { u = gld_agent(pr); } while ((int)(u >> 32) != jn);
                d = __uint_as_float((uint32_t)u);
            }
            d += __shfl_xor(d, 1); d += __shfl_xor(d, 2); d += __shfl_xor(d, 4);
            if (lane == 0 && d + cconst > 0.0f) ++count;
            ++jn;
        }
        if (lane == 0) out[b] = (float)count;
    } else {
        // ====== wave 9, q!=0: barrier-idle (early return would hang) ======
        for (int i = 0; i < len; ++i) wg_barrier();
    }
}

extern "C" void kernel_launch(void* const* d_in, const int* in_sizes, int n_in,
                              void* d_out, int out_size, void* d_ws, size_t ws_size,
                              hipStream_t stream) {
    const float* x    = (const float*)d_in[0];
    const int*   lens = (const int*)d_in[1];
    const float* W_ih = (const float*)d_in[2];
    const float* W_hh = (const float*)d_in[3];
    const float* b_ih = (const float*)d_in[4];
    const float* b_hh = (const float*)d_in[5];
    const float* W1   = (const float*)d_in[6];
    const float* b1   = (const float*)d_in[7];
    const float* W2   = (const float*)d_in[8];
    const float* b2   = (const float*)d_in[9];
    float* out = (float*)d_out;
    uint64_t* ws = (uint64_t*)d_ws;   // WS_U64 u64 = 295168 B

    ws_zero<<<dim3(145), dim3(256), 0, stream>>>(ws);
    rnn_seq<<<dim3(BB * QW), dim3(NTH), 0, stream>>>(
        x, lens, W_ih, W_hh, b_ih, b_hh, W1, b1, W2, b2, out, ws);
}